// Round 16
// baseline (252.388 us; speedup 1.0000x reference)
//
#include <hip/hip_runtime.h>
#include <hip/hip_bf16.h>

#define B_  2
#define S_  4096
#define E_  512
#define H_  8
#define DK_ 64
#define M_  8192  // B_*S_

typedef float f32x4  __attribute__((ext_vector_type(4)));
typedef float f32x16 __attribute__((ext_vector_type(16)));
typedef short s16x8  __attribute__((ext_vector_type(8)));
typedef short s16x4  __attribute__((ext_vector_type(4)));

static __device__ __forceinline__ short f2bf(float x) {
  __hip_bfloat16 h = __float2bfloat16(x);
  return __builtin_bit_cast(short, h);
}

static __device__ __forceinline__ f32x4 mfma32(s16x8 a, s16x8 b, f32x4 c) {
  return __builtin_amdgcn_mfma_f32_16x16x32_bf16(a, b, c, 0, 0, 0);
}

static __device__ __forceinline__ f32x16 mfma3232(s16x8 a, s16x8 b, f32x16 c) {
  return __builtin_amdgcn_mfma_f32_32x32x16_bf16(a, b, c, 0, 0, 0);
}

// 2^x. Compiler intrinsic (proper hazard handling — raw inline-asm v_exp_f32
// was round-3's correctness bug). Fallback: e^(x ln2) via __expf.
static __device__ __forceinline__ float fastexp2(float x) {
#if __has_builtin(__builtin_amdgcn_exp2f)
  return __builtin_amdgcn_exp2f(x);
#else
  return __expf(x * 0.69314718056f);
#endif
}

static __device__ __forceinline__ void gload_lds16(const void* g, void* l) {
  __builtin_amdgcn_global_load_lds(
      (const __attribute__((address_space(1))) unsigned int*)g,
      (__attribute__((address_space(3))) unsigned int*)l, 16, 0, 0);
}

// W [E][E] f32 row-major -> Wt bf16 [N=E][K=E] (transposed); y selects W.
__global__ __launch_bounds__(256) void conv_wT_all(
    const float* __restrict__ Wq, const float* __restrict__ Wk,
    const float* __restrict__ Wv, const float* __restrict__ Wo,
    short* __restrict__ Wt) {
  const float* W = (blockIdx.y == 0) ? Wq
                   : ((blockIdx.y == 1) ? Wk : ((blockIdx.y == 2) ? Wv : Wo));
  short* o = Wt + (size_t)blockIdx.y * (E_ * E_);
  int idx = blockIdx.x * 256 + threadIdx.x;
  int j = idx >> 9, k = idx & 511;
  o[idx] = f2bf(W[(size_t)k * E_ + j]);
}

// ------- GEMM core (bf16 A): 2-phase dbuf, BK=32, frag-gathered LDS -------
static __device__ __forceinline__ void gemm_core_512(
    const short* __restrict__ A, const short* __restrict__ Bt,
    short* As, short* Bs, int tm, int tn, f32x4 acc[4][4]) {
  const int tid = threadIdx.x;
  const int wave = tid >> 6, lane = tid & 63;
  const int c = lane & 15, g = lane >> 4;
  int fOff[2];
#pragma unroll
  for (int r = 0; r < 2; ++r) {
    const int f = wave * 2 + r;  // frag 0..7
    fOff[r] = ((f >> 2) * 64 + (f & 3) * 16 + c) * 512 + g * 8;
  }
  auto stg = [&](int p, int b) {
#pragma unroll
    for (int r = 0; r < 2; ++r) {
      const int f = wave * 2 + r;
      gload_lds16(A + (size_t)tm * 512 + p * 32 + fOff[r],
                  (char*)As + b * 8192 + f * 1024);
      gload_lds16(Bt + (size_t)tn * 512 + p * 32 + fOff[r],
                  (char*)Bs + b * 8192 + f * 1024);
    }
  };
  stg(0, 0);
  __syncthreads();
  for (int p = 0; p < 16; ++p) {
    if (p + 1 < 16) stg(p + 1, (p + 1) & 1);  // overlaps compute below
    const short* Ac = As + (p & 1) * 4096;
    const short* Bc = Bs + (p & 1) * 4096;
    s16x8 af[4], bfr[4];
#pragma unroll
    for (int i = 0; i < 4; ++i)
      af[i] = *(const s16x8*)(Ac + ((wave >> 1) * 4 + i) * 512 + lane * 8);
#pragma unroll
    for (int j = 0; j < 4; ++j)
      bfr[j] = *(const s16x8*)(Bc + ((wave & 1) * 4 + j) * 512 + lane * 8);
#pragma unroll
    for (int i = 0; i < 4; ++i)
#pragma unroll
      for (int j = 0; j < 4; ++j)
        acc[i][j] = mfma32(af[i], bfr[j], acc[i][j]);
    __syncthreads();
  }
}

// ------- GEMM core (f32 A, fused conversion): T14 reg-staged A ------------
static __device__ __forceinline__ void gemm_core_f32A(
    const float* __restrict__ A, const short* __restrict__ Bt,
    short* As, short* Bs, int tm, int tn, f32x4 acc[4][4]) {
  const int tid = threadIdx.x;
  const int wave = tid >> 6, lane = tid & 63;
  const int c = lane & 15, g = lane >> 4;
  int fOff[2];
#pragma unroll
  for (int r = 0; r < 2; ++r) {
    const int f = wave * 2 + r;
    fOff[r] = ((f >> 2) * 64 + (f & 3) * 16 + c) * 512 + g * 8;
  }
  auto stgB = [&](int p, int b) {
#pragma unroll
    for (int r = 0; r < 2; ++r)
      gload_lds16(Bt + (size_t)tn * 512 + p * 32 + fOff[r],
                  (char*)Bs + b * 8192 + (wave * 2 + r) * 1024);
  };
  float4 a0[2], a1[2];
  auto ldA = [&](int p) {
#pragma unroll
    for (int r = 0; r < 2; ++r) {
      const float* ap = A + (size_t)tm * 512 + p * 32 + fOff[r];
      a0[r] = *(const float4*)ap;
      a1[r] = *(const float4*)(ap + 4);
    }
  };
  auto wrA = [&](int b) {
#pragma unroll
    for (int r = 0; r < 2; ++r) {
      s16x8 w;
      w[0] = f2bf(a0[r].x); w[1] = f2bf(a0[r].y);
      w[2] = f2bf(a0[r].z); w[3] = f2bf(a0[r].w);
      w[4] = f2bf(a1[r].x); w[5] = f2bf(a1[r].y);
      w[6] = f2bf(a1[r].z); w[7] = f2bf(a1[r].w);
      *(s16x8*)((char*)As + b * 8192 + (wave * 2 + r) * 1024 + lane * 16) = w;
    }
  };
  ldA(0); stgB(0, 0); wrA(0);
  __syncthreads();
  for (int p = 0; p < 16; ++p) {
    if (p + 1 < 16) { ldA(p + 1); stgB(p + 1, (p + 1) & 1); }
    const short* Ac = As + (p & 1) * 4096;
    const short* Bc = Bs + (p & 1) * 4096;
    s16x8 af[4], bfr[4];
#pragma unroll
    for (int i = 0; i < 4; ++i)
      af[i] = *(const s16x8*)(Ac + ((wave >> 1) * 4 + i) * 512 + lane * 8);
#pragma unroll
    for (int j = 0; j < 4; ++j)
      bfr[j] = *(const s16x8*)(Bc + ((wave & 1) * 4 + j) * 512 + lane * 8);
#pragma unroll
    for (int i = 0; i < 4; ++i)
#pragma unroll
      for (int j = 0; j < 4; ++j)
        acc[i][j] = mfma32(af[i], bfr[j], acc[i][j]);
    if (p + 1 < 16) wrA((p + 1) & 1);  // into the buffer freed last barrier
    __syncthreads();
  }
}

// QKV projections from the ORIGINAL f32 inputs (conv pass fused away).
__global__ __launch_bounds__(256) void gemm_qkv(
    const float* __restrict__ Xq, const float* __restrict__ Xk,
    const float* __restrict__ Xv, const short* __restrict__ Wt,
    const float* __restrict__ bq, const float* __restrict__ bk,
    const float* __restrict__ bv,
    short* __restrict__ Qo, short* __restrict__ Ko, short* __restrict__ Vto) {
  __shared__ __align__(16) short As[2 * 4096];
  __shared__ __align__(16) short Bs[2 * 4096];
  const int z = blockIdx.z;
  const float* A = (z == 0) ? Xq : ((z == 1) ? Xk : Xv);
  const short* Bt = Wt + z * (E_ * E_);
  const float* bias = (z == 0) ? bq : ((z == 1) ? bk : bv);
  const int tm = blockIdx.x * 128, tn = blockIdx.y * 128;
  f32x4 acc[4][4] = {};
  gemm_core_f32A(A, Bt, As, Bs, tm, tn, acc);

  const int tid = threadIdx.x;
  const int wave = tid >> 6, lane = tid & 63;
  const int wm = (wave >> 1) * 64, wn = (wave & 1) * 64;
  const int c = lane & 15, g = lane >> 4;
#pragma unroll
  for (int i = 0; i < 4; ++i) {
#pragma unroll
    for (int j = 0; j < 4; ++j) {
      const int gc = tn + wn + j * 16 + c;
      const float bb = bias[gc];
      const int h = gc >> 6, dk = gc & 63;
      if (z == 2) {
        const int gr0 = tm + wm + i * 16 + g * 4;
        const int b = gr0 >> 12, s0 = gr0 & 4095;
        s16x4 v4;
#pragma unroll
        for (int r = 0; r < 4; ++r) v4[r] = f2bf(acc[i][j][r] + bb);
        *(s16x4*)&Vto[(size_t)((b * H_ + h) * DK_ + dk) * S_ + s0] = v4;
      } else {
#pragma unroll
        for (int r = 0; r < 4; ++r) {
          const int gr = tm + wm + i * 16 + g * 4 + r;
          const int b = gr >> 12, s = gr & 4095;
          float v = acc[i][j][r] + bb;
          if (z == 0) v *= 1.44269504f;  // Q *= log2(e)
          const short hv = f2bf(v);
          if (z == 1)
            Ko[(size_t)((b * H_ + h) * S_ + s) * DK_ + dk] = hv;
          else
            Qo[(size_t)((b * H_ + h) * S_ + s) * DK_ + dk] = hv;
        }
      }
    }
  }
}

// Output projection: out = AO(bf16) @ Wo + bo, f32 row-major.
__global__ __launch_bounds__(256) void gemm_out(
    const short* __restrict__ AO, const short* __restrict__ Wot,
    const float* __restrict__ bo, float* __restrict__ out) {
  __shared__ __align__(16) short As[2 * 4096];
  __shared__ __align__(16) short Bs[2 * 4096];
  const int tm = blockIdx.x * 128, tn = blockIdx.y * 128;
  f32x4 acc[4][4] = {};
  gemm_core_512(AO, Wot, As, Bs, tm, tn, acc);

  const int tid = threadIdx.x;
  const int wave = tid >> 6, lane = tid & 63;
  const int wm = (wave >> 1) * 64, wn = (wave & 1) * 64;
  const int c = lane & 15, g = lane >> 4;
#pragma unroll
  for (int i = 0; i < 4; ++i) {
#pragma unroll
    for (int j = 0; j < 4; ++j) {
      const int gc = tn + wn + j * 16 + c;
      const float bb = bo[gc];
#pragma unroll
      for (int r = 0; r < 4; ++r) {
        const int gr = tm + wm + i * 16 + g * 4 + r;
        out[(size_t)gr * E_ + gc] = acc[i][j][r] + bb;
      }
    }
  }
}

// ---- flash attention: tile-parity split, RACE-FREE epoch schedule --------
// r15 retry. r9-r14 carried a latent write-after-read race (stage issued
// BEFORE the window barrier, same epoch as other waves' ds_reads of the
// target buffer) — benign at 1 block/CU lockstep, corrupting at 2 blocks/CU
// skew (r15's 0.05 absmax). Fix: stage is issued AFTER the barrier.
//   prologue: stage(0,1); bar; stage(2,3)
//   window t2: read tiles t2,t2+1 -> bar(vmcnt0+lgkm0) -> stage(t2+4,t2+5)
// Write-after-read: buffers t2&3,(t2+1)&3 read before bar(t2), staged after
// it (barrier-separated). Read-after-write: tiles t2+2,t2+3 drained at
// bar(t2), read at window t2+2. In-flight DMA never aliases buffers being
// read (disjoint mod 4). Drain-0 per window measured perf-neutral (r10).
// Decomposition: 8 waves = 2 q-groups(64q) x 2 key-halves x 2 TILE
// PARITIES; 128 q/block; grid 32x16 = 512 blocks = 2/CU = 4 waves/SIMD
// (the occupancy experiment r15 failed to run). LDS 64KB (K 4x8K, V 4x8K).
// Merge: 4 partials (kh x ts) per q-group, plain addition (exact for
// no-max softmax), chunked via dead-LDS overlay.
__global__ __launch_bounds__(512, 4) void attn_fwd(
    const short* __restrict__ Q, const short* __restrict__ K,
    const short* __restrict__ Vt, short* __restrict__ O) {
  __shared__ __align__(16) char lds[65536];  // K 4x8K | V 4x8K; merge overlay
  const int tid = threadIdx.x;
  const int wave = tid >> 6, lane = tid & 63;
  const int qg = wave >> 2, kh = (wave >> 1) & 1, ts = wave & 1;
  const int qi = lane & 31, hi = lane >> 5;
  const int bh = blockIdx.y;
  const int b = bh >> 3, h = bh & 7;
  const int q0 = blockIdx.x * 128 + qg * 64;
  const short* Qp = Q + (size_t)bh * S_ * DK_;
  const short* Kp = K + (size_t)bh * S_ * DK_;
  const short* Vp = Vt + (size_t)bh * DK_ * S_;

  s16x8 qfL[4], qfH[4];
#pragma unroll
  for (int s = 0; s < 4; ++s) {
    qfL[s] = *(const s16x8*)(Qp + (size_t)(q0 + qi) * DK_ + s * 16 + hi * 8);
    qfH[s] = *(const s16x8*)(Qp + (size_t)(q0 + 32 + qi) * DK_ + s * 16 + hi * 8);
  }

  f32x16 o00 = {}, o01 = {}, o10 = {}, o11 = {};  // o[dkh][qh]
  float lsL = 0.f, lsH = 0.f;                     // denominator partials

  // per-lane gather offsets: wave stages K frag `wave` and V frag `wave`
  int kOff, vOff;
  {
    const int j = wave;                    // 0..7
    const int row = (j >> 2) * 32 + qi;    // K source row (pre-tau)
    const int srow = (row & 32) | ((row & 8) << 1) | ((row & 4) << 1) |
                     ((row & 16) >> 2) | (row & 3);  // tau permute
    kOff = srow * DK_ + (j & 3) * 16 + hi * 8;
    vOff = ((j >> 2) * 32 + qi) * S_ + ((j >> 1) & 1) * 32 +
           (j & 1) * 16 + hi * 8;
  }

  // stage tile kt: K frags -> lds[(kt%4)*8K], V frags -> lds[32K+(kt%4)*8K]
  auto stage = [&](int kt) {
    gload_lds16(Kp + (size_t)kt * 64 * DK_ + kOff,
                lds + (kt & 3) * 8192 + wave * 1024);
    gload_lds16(Vp + (size_t)kt * 64 + vOff,
                lds + 32768 + (kt & 3) * 8192 + wave * 1024);
  };

  // full-drain barrier: all DMA landed, all LDS reads done, then sync.
  auto barD = [&]() {
    asm volatile("s_waitcnt vmcnt(0) lgkmcnt(0)" ::: "memory");
    __builtin_amdgcn_s_barrier();
  };

  const int lbK = kh * 4096 + (lane << 4);

  auto qk = [&](int t, f32x16& sL, f32x16& sH) {
    const char* Kc = lds + (t & 3) * 8192 + lbK;
    f32x16 a = {}, c = {};
    __builtin_amdgcn_s_setprio(1);
#pragma unroll
    for (int s = 0; s < 4; ++s) {
      s16x8 ka = *(const s16x8*)(Kc + s * 1024);
      a = mfma3232(ka, qfL[s], a);
      c = mfma3232(ka, qfH[s], c);
    }
    __builtin_amdgcn_s_setprio(0);
    sL = a; sH = c;
  };

  auto softpv = [&](const f32x16& sL, const f32x16& sH, int t) {
    const char* Vc = lds + 32768 + (t & 3) * 8192 + kh * 2048 + (lane << 4);
    float pL[16], pH[16];
#pragma unroll
    for (int r = 0; r < 16; ++r) { pL[r] = fastexp2(sL[r]); pH[r] = fastexp2(sH[r]); }
    float aL = 0.f, aH = 0.f;
#pragma unroll
    for (int r = 0; r < 16; ++r) { aL += pL[r]; aH += pH[r]; }
    lsL += aL; lsH += aH;
    s16x8 pbL[2], pbH[2];
#pragma unroll
    for (int ks = 0; ks < 2; ++ks)
#pragma unroll
      for (int j = 0; j < 8; ++j) {
        const int r = (j & 3) | (ks << 2) | ((j >> 2) << 3);
        pbL[ks][j] = f2bf(pL[r]);
        pbH[ks][j] = f2bf(pH[r]);
      }
    __builtin_amdgcn_s_setprio(1);
#pragma unroll
    for (int ks = 0; ks < 2; ++ks) {
      s16x8 va0 = *(const s16x8*)(Vc + ks * 1024);          // dk 0-31
      s16x8 va1 = *(const s16x8*)(Vc + 4096 + ks * 1024);   // dk 32-63
      o00 = mfma3232(va0, pbL[ks], o00);
      o01 = mfma3232(va0, pbH[ks], o01);
      o10 = mfma3232(va1, pbL[ks], o10);
      o11 = mfma3232(va1, pbH[ks], o11);
    }
    __builtin_amdgcn_s_setprio(0);
  };

  const int NT = S_ / 64;
  f32x16 sA0, sA1;

  // prologue: tiles 0,1 staged+drained; 2,3 in flight (land by bar(0))
  stage(0); stage(1);
  barD();
  stage(2); stage(3);

  for (int t2 = 0; t2 < NT; t2 += 2) {
    const int t = t2 + ts;  // this wave's parity tile
    qk(t, sA0, sA1);
    softpv(sA0, sA1, t);
    barD();  // drains DMA for tiles t2+2,t2+3; all reads of t2,t2+1 done
    if (t2 + 4 < NT) { stage(t2 + 4); stage(t2 + 5); }  // overwrite SAFE now
  }

  // fold the two hi-slices (16 keys each) of this wave's partial
  lsL += __shfl_xor(lsL, 32);
  lsH += __shfl_xor(lsH, 32);

  // ---- merge 4 partials (kh x ts) per q-group: plain addition (exact for
  // no-max softmax). Chunked via dead LDS: 6 writer regions x 64 x 36 f32.
  float* mrg = (float*)lds;
  const int widx = kh * 2 + ts;  // 0 = reducer
  const int miW = ((qg * 3 + (widx - 1)) * 64 + lane) * 36;
  __syncthreads();  // all waves past loop; no DMA outstanding (last barD)
  if (widx) {
#pragma unroll
    for (int r = 0; r < 4; ++r) {
      *(f32x4*)(mrg + miW + r * 4) =
          f32x4{o00[r * 4], o00[r * 4 + 1], o00[r * 4 + 2], o00[r * 4 + 3]};
      *(f32x4*)(mrg + miW + 16 + r * 4) =
          f32x4{o01[r * 4], o01[r * 4 + 1], o01[r * 4 + 2], o01[r * 4 + 3]};
    }
    mrg[miW + 32] = lsL;
    mrg[miW + 33] = lsH;
  }
  __syncthreads();
  float rlL = 0.f, rlH = 0.f;
  if (!widx) {
#pragma unroll
    for (int w2 = 0; w2 < 3; ++w2) {
      const int mi2 = ((qg * 3 + w2) * 64 + lane) * 36;
#pragma unroll
      for (int r = 0; r < 16; ++r) {
        o00[r] += mrg[mi2 + r];
        o01[r] += mrg[mi2 + 16 + r];
      }
      lsL += mrg[mi2 + 32];
      lsH += mrg[mi2 + 33];
    }
    rlL = 1.f / lsL;
    rlH = 1.f / lsH;
  }
  __syncthreads();
  if (widx) {
#pragma unroll
    for (int r = 0; r < 4; ++r) {
      *(f32x4*)(mrg + miW + r * 4) =
          f32x4{o10[r * 4], o10[r * 4 + 1], o10[r * 4 + 2], o10[r * 4 + 3]};
      *(f32x4*)(mrg + miW + 16 + r * 4) =
          f32x4{o11[r * 4], o11[r * 4 + 1], o11[r * 4 + 2], o11[r * 4 + 3]};
    }
  }
  __syncthreads();
  if (!widx) {
#pragma unroll
    for (int w2 = 0; w2 < 3; ++w2) {
      const int mi2 = ((qg * 3 + w2) * 64 + lane) * 36;
#pragma unroll
      for (int r = 0; r < 16; ++r) {
        o10[r] += mrg[mi2 + r];
        o11[r] += mrg[mi2 + 16 + r];
      }
    }
    // write out: q row = q0 + qh*32 + qi; dk = dkh*32 + rr*8 + hi*4 + e
    short* OpL = O + ((size_t)(b * S_ + q0 + qi)) * E_ + h * DK_;
    short* OpH = O + ((size_t)(b * S_ + q0 + 32 + qi)) * E_ + h * DK_;
#pragma unroll
    for (int rr = 0; rr < 4; ++rr) {
      s16x4 vL0, vL1, vH0, vH1;
#pragma unroll
      for (int e = 0; e < 4; ++e) {
        vL0[e] = f2bf(o00[rr * 4 + e] * rlL);
        vL1[e] = f2bf(o10[rr * 4 + e] * rlL);
        vH0[e] = f2bf(o01[rr * 4 + e] * rlH);
        vH1[e] = f2bf(o11[rr * 4 + e] * rlH);
      }
      *(s16x4*)(OpL + rr * 8 + hi * 4) = vL0;
      *(s16x4*)(OpL + 32 + rr * 8 + hi * 4) = vL1;
      *(s16x4*)(OpH + rr * 8 + hi * 4) = vH0;
      *(s16x4*)(OpH + 32 + rr * 8 + hi * 4) = vH1;
    }
  }
}

// ---------------- launch ----------------
extern "C" void kernel_launch(void* const* d_in, const int* in_sizes, int n_in,
                              void* d_out, int out_size, void* d_ws, size_t ws_size,
                              hipStream_t stream) {
  const float* query  = (const float*)d_in[0];
  const float* key_in = (const float*)d_in[1];
  const float* value  = (const float*)d_in[2];
  const float* Wq = (const float*)d_in[3];
  const float* bq = (const float*)d_in[4];
  const float* Wk = (const float*)d_in[5];
  const float* bk = (const float*)d_in[6];
  const float* Wv = (const float*)d_in[7];
  const float* bv = (const float*)d_in[8];
  const float* Wo = (const float*)d_in[9];
  const float* bo = (const float*)d_in[10];
  float* out = (float*)d_out;

  const size_t NA = (size_t)M_ * E_;  // 4,194,304
  short* ws  = (short*)d_ws;
  short* Wt  = ws;                    // bf16 W^T, q/k/v/o fused [4E][E]
  short* Wot = Wt + 3 * E_ * E_;
  short* Qb  = Wt + 4 * E_ * E_;      // bf16 [B,H,S,DK] (pre-scaled log2e)
  short* Kb  = Qb + NA;               // bf16 [B,H,S,DK]
  short* Vtb = Kb + NA;               // bf16 [B,H,DK,S]
  short* AO  = Vtb + NA;              // bf16 attn out [B,S,E]

  conv_wT_all<<<dim3(E_ * E_ / 256, 4), 256, 0, stream>>>(Wq, Wk, Wv, Wo, Wt);

  gemm_qkv<<<dim3(M_ / 128, E_ / 128, 3), 256, 0, stream>>>(
      query, key_in, value, Wt, bq, bk, bv, Qb, Kb, Vtb);
  attn_fwd<<<dim3(S_ / 128, B_ * H_), 512, 0, stream>>>(Qb, Kb, Vtb, AO);
  gemm_out<<<dim3(M_ / 128, E_ / 128), 256, 0, stream>>>(AO, Wot, bo, out);
}

// Round 17
// 148.695 us; speedup vs baseline: 1.6974x; 1.6974x over previous
//
#include <hip/hip_runtime.h>
#include <hip/hip_bf16.h>

#define B_  2
#define S_  4096
#define E_  512
#define H_  8
#define DK_ 64
#define M_  8192  // B_*S_

typedef float f32x4  __attribute__((ext_vector_type(4)));
typedef float f32x16 __attribute__((ext_vector_type(16)));
typedef short s16x8  __attribute__((ext_vector_type(8)));
typedef short s16x4  __attribute__((ext_vector_type(4)));

static __device__ __forceinline__ short f2bf(float x) {
  __hip_bfloat16 h = __float2bfloat16(x);
  return __builtin_bit_cast(short, h);
}

static __device__ __forceinline__ f32x4 mfma32(s16x8 a, s16x8 b, f32x4 c) {
  return __builtin_amdgcn_mfma_f32_16x16x32_bf16(a, b, c, 0, 0, 0);
}

static __device__ __forceinline__ f32x16 mfma3232(s16x8 a, s16x8 b, f32x16 c) {
  return __builtin_amdgcn_mfma_f32_32x32x16_bf16(a, b, c, 0, 0, 0);
}

// 2^x. Compiler intrinsic (proper hazard handling — raw inline-asm v_exp_f32
// was round-3's correctness bug). Fallback: e^(x ln2) via __expf.
static __device__ __forceinline__ float fastexp2(float x) {
#if __has_builtin(__builtin_amdgcn_exp2f)
  return __builtin_amdgcn_exp2f(x);
#else
  return __expf(x * 0.69314718056f);
#endif
}

static __device__ __forceinline__ void gload_lds16(const void* g, void* l) {
  __builtin_amdgcn_global_load_lds(
      (const __attribute__((address_space(1))) unsigned int*)g,
      (__attribute__((address_space(3))) unsigned int*)l, 16, 0, 0);
}

// W [E][E] f32 row-major -> Wt bf16 [N=E][K=E] (transposed); y selects W.
__global__ __launch_bounds__(256) void conv_wT_all(
    const float* __restrict__ Wq, const float* __restrict__ Wk,
    const float* __restrict__ Wv, const float* __restrict__ Wo,
    short* __restrict__ Wt) {
  const float* W = (blockIdx.y == 0) ? Wq
                   : ((blockIdx.y == 1) ? Wk : ((blockIdx.y == 2) ? Wv : Wo));
  short* o = Wt + (size_t)blockIdx.y * (E_ * E_);
  int idx = blockIdx.x * 256 + threadIdx.x;
  int j = idx >> 9, k = idx & 511;
  o[idx] = f2bf(W[(size_t)k * E_ + j]);
}

// ------- GEMM core (bf16 A): 2-phase dbuf, BK=32, frag-gathered LDS -------
static __device__ __forceinline__ void gemm_core_512(
    const short* __restrict__ A, const short* __restrict__ Bt,
    short* As, short* Bs, int tm, int tn, f32x4 acc[4][4]) {
  const int tid = threadIdx.x;
  const int wave = tid >> 6, lane = tid & 63;
  const int c = lane & 15, g = lane >> 4;
  int fOff[2];
#pragma unroll
  for (int r = 0; r < 2; ++r) {
    const int f = wave * 2 + r;  // frag 0..7
    fOff[r] = ((f >> 2) * 64 + (f & 3) * 16 + c) * 512 + g * 8;
  }
  auto stg = [&](int p, int b) {
#pragma unroll
    for (int r = 0; r < 2; ++r) {
      const int f = wave * 2 + r;
      gload_lds16(A + (size_t)tm * 512 + p * 32 + fOff[r],
                  (char*)As + b * 8192 + f * 1024);
      gload_lds16(Bt + (size_t)tn * 512 + p * 32 + fOff[r],
                  (char*)Bs + b * 8192 + f * 1024);
    }
  };
  stg(0, 0);
  __syncthreads();
  for (int p = 0; p < 16; ++p) {
    if (p + 1 < 16) stg(p + 1, (p + 1) & 1);  // overlaps compute below
    const short* Ac = As + (p & 1) * 4096;
    const short* Bc = Bs + (p & 1) * 4096;
    s16x8 af[4], bfr[4];
#pragma unroll
    for (int i = 0; i < 4; ++i)
      af[i] = *(const s16x8*)(Ac + ((wave >> 1) * 4 + i) * 512 + lane * 8);
#pragma unroll
    for (int j = 0; j < 4; ++j)
      bfr[j] = *(const s16x8*)(Bc + ((wave & 1) * 4 + j) * 512 + lane * 8);
#pragma unroll
    for (int i = 0; i < 4; ++i)
#pragma unroll
      for (int j = 0; j < 4; ++j)
        acc[i][j] = mfma32(af[i], bfr[j], acc[i][j]);
    __syncthreads();
  }
}

// ------- GEMM core (f32 A, fused conversion): T14 reg-staged A ------------
static __device__ __forceinline__ void gemm_core_f32A(
    const float* __restrict__ A, const short* __restrict__ Bt,
    short* As, short* Bs, int tm, int tn, f32x4 acc[4][4]) {
  const int tid = threadIdx.x;
  const int wave = tid >> 6, lane = tid & 63;
  const int c = lane & 15, g = lane >> 4;
  int fOff[2];
#pragma unroll
  for (int r = 0; r < 2; ++r) {
    const int f = wave * 2 + r;
    fOff[r] = ((f >> 2) * 64 + (f & 3) * 16 + c) * 512 + g * 8;
  }
  auto stgB = [&](int p, int b) {
#pragma unroll
    for (int r = 0; r < 2; ++r)
      gload_lds16(Bt + (size_t)tn * 512 + p * 32 + fOff[r],
                  (char*)Bs + b * 8192 + (wave * 2 + r) * 1024);
  };
  float4 a0[2], a1[2];
  auto ldA = [&](int p) {
#pragma unroll
    for (int r = 0; r < 2; ++r) {
      const float* ap = A + (size_t)tm * 512 + p * 32 + fOff[r];
      a0[r] = *(const float4*)ap;
      a1[r] = *(const float4*)(ap + 4);
    }
  };
  auto wrA = [&](int b) {
#pragma unroll
    for (int r = 0; r < 2; ++r) {
      s16x8 w;
      w[0] = f2bf(a0[r].x); w[1] = f2bf(a0[r].y);
      w[2] = f2bf(a0[r].z); w[3] = f2bf(a0[r].w);
      w[4] = f2bf(a1[r].x); w[5] = f2bf(a1[r].y);
      w[6] = f2bf(a1[r].z); w[7] = f2bf(a1[r].w);
      *(s16x8*)((char*)As + b * 8192 + (wave * 2 + r) * 1024 + lane * 16) = w;
    }
  };
  ldA(0); stgB(0, 0); wrA(0);
  __syncthreads();
  for (int p = 0; p < 16; ++p) {
    if (p + 1 < 16) { ldA(p + 1); stgB(p + 1, (p + 1) & 1); }
    const short* Ac = As + (p & 1) * 4096;
    const short* Bc = Bs + (p & 1) * 4096;
    s16x8 af[4], bfr[4];
#pragma unroll
    for (int i = 0; i < 4; ++i)
      af[i] = *(const s16x8*)(Ac + ((wave >> 1) * 4 + i) * 512 + lane * 8);
#pragma unroll
    for (int j = 0; j < 4; ++j)
      bfr[j] = *(const s16x8*)(Bc + ((wave & 1) * 4 + j) * 512 + lane * 8);
#pragma unroll
    for (int i = 0; i < 4; ++i)
#pragma unroll
      for (int j = 0; j < 4; ++j)
        acc[i][j] = mfma32(af[i], bfr[j], acc[i][j]);
    if (p + 1 < 16) wrA((p + 1) & 1);  // into the buffer freed last barrier
    __syncthreads();
  }
}

// QKV projections from the ORIGINAL f32 inputs (conv pass fused away).
__global__ __launch_bounds__(256) void gemm_qkv(
    const float* __restrict__ Xq, const float* __restrict__ Xk,
    const float* __restrict__ Xv, const short* __restrict__ Wt,
    const float* __restrict__ bq, const float* __restrict__ bk,
    const float* __restrict__ bv,
    short* __restrict__ Qo, short* __restrict__ Ko, short* __restrict__ Vto) {
  __shared__ __align__(16) short As[2 * 4096];
  __shared__ __align__(16) short Bs[2 * 4096];
  const int z = blockIdx.z;
  const float* A = (z == 0) ? Xq : ((z == 1) ? Xk : Xv);
  const short* Bt = Wt + z * (E_ * E_);
  const float* bias = (z == 0) ? bq : ((z == 1) ? bk : bv);
  const int tm = blockIdx.x * 128, tn = blockIdx.y * 128;
  f32x4 acc[4][4] = {};
  gemm_core_f32A(A, Bt, As, Bs, tm, tn, acc);

  const int tid = threadIdx.x;
  const int wave = tid >> 6, lane = tid & 63;
  const int wm = (wave >> 1) * 64, wn = (wave & 1) * 64;
  const int c = lane & 15, g = lane >> 4;
#pragma unroll
  for (int i = 0; i < 4; ++i) {
#pragma unroll
    for (int j = 0; j < 4; ++j) {
      const int gc = tn + wn + j * 16 + c;
      const float bb = bias[gc];
      const int h = gc >> 6, dk = gc & 63;
      if (z == 2) {
        const int gr0 = tm + wm + i * 16 + g * 4;
        const int b = gr0 >> 12, s0 = gr0 & 4095;
        s16x4 v4;
#pragma unroll
        for (int r = 0; r < 4; ++r) v4[r] = f2bf(acc[i][j][r] + bb);
        *(s16x4*)&Vto[(size_t)((b * H_ + h) * DK_ + dk) * S_ + s0] = v4;
      } else {
#pragma unroll
        for (int r = 0; r < 4; ++r) {
          const int gr = tm + wm + i * 16 + g * 4 + r;
          const int b = gr >> 12, s = gr & 4095;
          float v = acc[i][j][r] + bb;
          if (z == 0) v *= 1.44269504f;  // Q *= log2(e)
          const short hv = f2bf(v);
          if (z == 1)
            Ko[(size_t)((b * H_ + h) * S_ + s) * DK_ + dk] = hv;
          else
            Qo[(size_t)((b * H_ + h) * S_ + s) * DK_ + dk] = hv;
        }
      }
    }
  }
}

// Output projection: out = AO(bf16) @ Wo + bo, f32 row-major.
__global__ __launch_bounds__(256) void gemm_out(
    const short* __restrict__ AO, const short* __restrict__ Wot,
    const float* __restrict__ bo, float* __restrict__ out) {
  __shared__ __align__(16) short As[2 * 4096];
  __shared__ __align__(16) short Bs[2 * 4096];
  const int tm = blockIdx.x * 128, tn = blockIdx.y * 128;
  f32x4 acc[4][4] = {};
  gemm_core_512(AO, Wot, As, Bs, tm, tn, acc);

  const int tid = threadIdx.x;
  const int wave = tid >> 6, lane = tid & 63;
  const int wm = (wave >> 1) * 64, wn = (wave & 1) * 64;
  const int c = lane & 15, g = lane >> 4;
#pragma unroll
  for (int i = 0; i < 4; ++i) {
#pragma unroll
    for (int j = 0; j < 4; ++j) {
      const int gc = tn + wn + j * 16 + c;
      const float bb = bo[gc];
#pragma unroll
      for (int r = 0; r < 4; ++r) {
        const int gr = tm + wm + i * 16 + g * 4 + r;
        out[(size_t)gr * E_ + gc] = acc[i][j][r] + bb;
      }
    }
  }
}

// ---- flash attention: r14 structure + RACE-FREE epoch schedule ----------
// Final form. 8 waves = 4 q-groups(64q) x 2 key-halves, 256 q/block,
// grid 16x16 = 1 block/CU (r16 proved 4 waves/SIMD forces register spill:
// VGPR 64 + 380MB scratch traffic; 2 waves/SIMD is the feasible max for
// this tile). 2-tile windows, K/V 6-buffered (96KB LDS).
// RACE-FREE schedule (r15 lesson — stage only AFTER the barrier):
//   prologue: stage(0..3); barD
//   window t: qk(t),qk(t+1); softpv(t),softpv(t+1); barD; stage(t+4,t+5)
// Every buffer write is 2 barriers after that buffer's last read; every
// read is 1 full window after its DMA was drained (barD = vmcnt0+lgkm0;
// drain-0 vs counted measured neutral in r10).
// Denominator via ones-MFMA (lacc): C[row][col=q] = sum_k P[k][q] — all
// rows identical => lacc[0] is the per-q denominator; removes 32 VALU adds
// + 2 shfl per wave-tile from the busiest pipe (matrix pipe has headroom).
// No-max softmax (Q pre-scaled by log2 e; shift-invariant, |s|<~45);
// key-half partials merge by plain addition via dead-LDS overlay.
__global__ __launch_bounds__(512, 2) void attn_fwd(
    const short* __restrict__ Q, const short* __restrict__ K,
    const short* __restrict__ Vt, short* __restrict__ O) {
  __shared__ __align__(16) char lds[98304];  // K 6x8K | V 6x8K; merge overlay
  const int tid = threadIdx.x;
  const int wave = tid >> 6, lane = tid & 63;
  const int g = wave >> 1, kh = wave & 1;
  const int qi = lane & 31, hi = lane >> 5;
  const int bh = blockIdx.y;
  const int b = bh >> 3, h = bh & 7;
  const int q0 = blockIdx.x * 256 + g * 64;
  const short* Qp = Q + (size_t)bh * S_ * DK_;
  const short* Kp = K + (size_t)bh * S_ * DK_;
  const short* Vp = Vt + (size_t)bh * DK_ * S_;

  s16x8 qfL[4], qfH[4];
#pragma unroll
  for (int s = 0; s < 4; ++s) {
    qfL[s] = *(const s16x8*)(Qp + (size_t)(q0 + qi) * DK_ + s * 16 + hi * 8);
    qfH[s] = *(const s16x8*)(Qp + (size_t)(q0 + 32 + qi) * DK_ + s * 16 + hi * 8);
  }

  f32x16 o00 = {}, o01 = {}, o10 = {}, o11 = {};  // o[dkh][qh]
  f32x16 laccL = {}, laccH = {};                  // denominators (ones-MFMA)
  s16x8 ones;
#pragma unroll
  for (int e = 0; e < 8; ++e) ones[e] = (short)0x3F80;

  // per-lane gather offsets: wave stages K frag `wave` and V frag `wave`
  int kOff, vOff;
  {
    const int j = wave;                    // 0..7
    const int row = (j >> 2) * 32 + qi;    // K source row (pre-tau)
    const int srow = (row & 32) | ((row & 8) << 1) | ((row & 4) << 1) |
                     ((row & 16) >> 2) | (row & 3);  // tau permute
    kOff = srow * DK_ + (j & 3) * 16 + hi * 8;
    vOff = ((j >> 2) * 32 + qi) * S_ + ((j >> 1) & 1) * 32 +
           (j & 1) * 16 + hi * 8;
  }

  // stage tile kt: K frags -> lds[(kt%6)*8K], V frags -> lds[48K+(kt%6)*8K]
  auto stage = [&](int kt) {
    gload_lds16(Kp + (size_t)kt * 64 * DK_ + kOff,
                lds + (kt % 6) * 8192 + wave * 1024);
    gload_lds16(Vp + (size_t)kt * 64 + vOff,
                lds + 49152 + (kt % 6) * 8192 + wave * 1024);
  };

  // full-drain barrier: all DMA landed, all LDS reads done, then sync.
  auto barD = [&]() {
    asm volatile("s_waitcnt vmcnt(0) lgkmcnt(0)" ::: "memory");
    __builtin_amdgcn_s_barrier();
  };

  const int lbK = kh * 4096 + (lane << 4);

  auto qk = [&](int t, f32x16& sL, f32x16& sH) {
    const char* Kc = lds + (t % 6) * 8192 + lbK;
    f32x16 a = {}, c = {};
    __builtin_amdgcn_s_setprio(1);
#pragma unroll
    for (int s = 0; s < 4; ++s) {
      s16x8 ka = *(const s16x8*)(Kc + s * 1024);
      a = mfma3232(ka, qfL[s], a);
      c = mfma3232(ka, qfH[s], c);
    }
    __builtin_amdgcn_s_setprio(0);
    sL = a; sH = c;
  };

  auto softpv = [&](const f32x16& sL, const f32x16& sH, int t) {
    const char* Vc = lds + 49152 + (t % 6) * 8192 + kh * 2048 + (lane << 4);
    float pL[16], pH[16];
#pragma unroll
    for (int r = 0; r < 16; ++r) { pL[r] = fastexp2(sL[r]); pH[r] = fastexp2(sH[r]); }
    s16x8 pbL[2], pbH[2];
#pragma unroll
    for (int ks = 0; ks < 2; ++ks)
#pragma unroll
      for (int j = 0; j < 8; ++j) {
        const int r = (j & 3) | (ks << 2) | ((j >> 2) << 3);
        pbL[ks][j] = f2bf(pL[r]);
        pbH[ks][j] = f2bf(pH[r]);
      }
    __builtin_amdgcn_s_setprio(1);
#pragma unroll
    for (int ks = 0; ks < 2; ++ks) {
      s16x8 va0 = *(const s16x8*)(Vc + ks * 1024);          // dk 0-31
      s16x8 va1 = *(const s16x8*)(Vc + 4096 + ks * 1024);   // dk 32-63
      o00 = mfma3232(va0, pbL[ks], o00);
      o01 = mfma3232(va0, pbH[ks], o01);
      o10 = mfma3232(va1, pbL[ks], o10);
      o11 = mfma3232(va1, pbH[ks], o11);
      laccL = mfma3232(ones, pbL[ks], laccL);
      laccH = mfma3232(ones, pbH[ks], laccH);
    }
    __builtin_amdgcn_s_setprio(0);
  };

  const int NT = S_ / 64;
  f32x16 sA0, sA1, sB0, sB1;

  // prologue: tiles 0..3 staged + fully drained
  stage(0); stage(1); stage(2); stage(3);
  barD();

  for (int t = 0; t < NT; t += 2) {
    qk(t, sA0, sA1);
    qk(t + 1, sB0, sB1);
    softpv(sA0, sA1, t);
    softpv(sB0, sB1, t + 1);
    barD();  // all reads of t,t+1 done block-wide; DMA t+2,t+3 landed
    if (t + 4 < NT) { stage(t + 4); stage(t + 5); }  // overwrite is SAFE
  }

  const float lsL = laccL[0], lsH = laccH[0];

  // ---- key-half merge: plain addition (no-max softmax partials exact) ----
  float* mrg = (float*)lds;
  const int mi = (g * 64 + lane) * 36;
  __syncthreads();  // no DMA outstanding (last barD); all waves past loop
  if (kh) {
#pragma unroll
    for (int r = 0; r < 4; ++r) {
      *(f32x4*)(mrg + mi + r * 4) =
          f32x4{o00[r * 4], o00[r * 4 + 1], o00[r * 4 + 2], o00[r * 4 + 3]};
      *(f32x4*)(mrg + mi + 16 + r * 4) =
          f32x4{o01[r * 4], o01[r * 4 + 1], o01[r * 4 + 2], o01[r * 4 + 3]};
    }
    mrg[mi + 32] = lsL;
    mrg[mi + 33] = lsH;
  }
  __syncthreads();
  float rlL = 0.f, rlH = 0.f;
  if (!kh) {
    float dL = lsL, dH = lsH;
#pragma unroll
    for (int r = 0; r < 16; ++r) {
      o00[r] += mrg[mi + r];
      o01[r] += mrg[mi + 16 + r];
    }
    dL += mrg[mi + 32];
    dH += mrg[mi + 33];
    rlL = 1.f / dL;
    rlH = 1.f / dH;
  }
  __syncthreads();
  if (kh) {
#pragma unroll
    for (int r = 0; r < 4; ++r) {
      *(f32x4*)(mrg + mi + r * 4) =
          f32x4{o10[r * 4], o10[r * 4 + 1], o10[r * 4 + 2], o10[r * 4 + 3]};
      *(f32x4*)(mrg + mi + 16 + r * 4) =
          f32x4{o11[r * 4], o11[r * 4 + 1], o11[r * 4 + 2], o11[r * 4 + 3]};
    }
  }
  __syncthreads();
  if (!kh) {
#pragma unroll
    for (int r = 0; r < 16; ++r) {
      o10[r] += mrg[mi + r];
      o11[r] += mrg[mi + 16 + r];
    }
    // write out: q row = q0 + qh*32 + qi; dk = dkh*32 + rr*8 + hi*4 + e
    short* OpL = O + ((size_t)(b * S_ + q0 + qi)) * E_ + h * DK_;
    short* OpH = O + ((size_t)(b * S_ + q0 + 32 + qi)) * E_ + h * DK_;
#pragma unroll
    for (int rr = 0; rr < 4; ++rr) {
      s16x4 vL0, vL1, vH0, vH1;
#pragma unroll
      for (int e = 0; e < 4; ++e) {
        vL0[e] = f2bf(o00[rr * 4 + e] * rlL);
        vL1[e] = f2bf(o10[rr * 4 + e] * rlL);
        vH0[e] = f2bf(o01[rr * 4 + e] * rlH);
        vH1[e] = f2bf(o11[rr * 4 + e] * rlH);
      }
      *(s16x4*)(OpL + rr * 8 + hi * 4) = vL0;
      *(s16x4*)(OpL + 32 + rr * 8 + hi * 4) = vL1;
      *(s16x4*)(OpH + rr * 8 + hi * 4) = vH0;
      *(s16x4*)(OpH + 32 + rr * 8 + hi * 4) = vH1;
    }
  }
}

// ---------------- launch ----------------
extern "C" void kernel_launch(void* const* d_in, const int* in_sizes, int n_in,
                              void* d_out, int out_size, void* d_ws, size_t ws_size,
                              hipStream_t stream) {
  const float* query  = (const float*)d_in[0];
  const float* key_in = (const float*)d_in[1];
  const float* value  = (const float*)d_in[2];
  const float* Wq = (const float*)d_in[3];
  const float* bq = (const float*)d_in[4];
  const float* Wk = (const float*)d_in[5];
  const float* bk = (const float*)d_in[6];
  const float* Wv = (const float*)d_in[7];
  const float* bv = (const float*)d_in[8];
  const float* Wo = (const float*)d_in[9];
  const float* bo = (const float*)d_in[10];
  float* out = (float*)d_out;

  const size_t NA = (size_t)M_ * E_;  // 4,194,304
  short* ws  = (short*)d_ws;
  short* Wt  = ws;                    // bf16 W^T, q/k/v/o fused [4E][E]
  short* Wot = Wt + 3 * E_ * E_;
  short* Qb  = Wt + 4 * E_ * E_;      // bf16 [B,H,S,DK] (pre-scaled log2e)
  short* Kb  = Qb + NA;               // bf16 [B,H,S,DK]
  short* Vtb = Kb + NA;               // bf16 [B,H,DK,S]
  short* AO  = Vtb + NA;              // bf16 attn out [B,S,E]

  conv_wT_all<<<dim3(E_ * E_ / 256, 4), 256, 0, stream>>>(Wq, Wk, Wv, Wo, Wt);

  gemm_qkv<<<dim3(M_ / 128, E_ / 128, 3), 256, 0, stream>>>(
      query, key_in, value, Wt, bq, bk, bv, Qb, Kb, Vtb);
  attn_fwd<<<dim3(S_ / 256, B_ * H_), 512, 0, stream>>>(Qb, Kb, Vtb, AO);
  gemm_out<<<dim3(M_ / 128, E_ / 128), 256, 0, stream>>>(AO, Wot, bo, out);
}

// Round 18
// 144.803 us; speedup vs baseline: 1.7430x; 1.0269x over previous
//
#include <hip/hip_runtime.h>
#include <hip/hip_bf16.h>

#define B_  2
#define S_  4096
#define E_  512
#define H_  8
#define DK_ 64
#define M_  8192  // B_*S_

typedef float f32x4  __attribute__((ext_vector_type(4)));
typedef float f32x16 __attribute__((ext_vector_type(16)));
typedef short s16x8  __attribute__((ext_vector_type(8)));
typedef short s16x4  __attribute__((ext_vector_type(4)));

static __device__ __forceinline__ short f2bf(float x) {
  __hip_bfloat16 h = __float2bfloat16(x);
  return __builtin_bit_cast(short, h);
}

static __device__ __forceinline__ f32x4 mfma32(s16x8 a, s16x8 b, f32x4 c) {
  return __builtin_amdgcn_mfma_f32_16x16x32_bf16(a, b, c, 0, 0, 0);
}

static __device__ __forceinline__ f32x16 mfma3232(s16x8 a, s16x8 b, f32x16 c) {
  return __builtin_amdgcn_mfma_f32_32x32x16_bf16(a, b, c, 0, 0, 0);
}

// 2^x. Compiler intrinsic (proper hazard handling — raw inline-asm v_exp_f32
// was round-3's correctness bug). Fallback: e^(x ln2) via __expf.
static __device__ __forceinline__ float fastexp2(float x) {
#if __has_builtin(__builtin_amdgcn_exp2f)
  return __builtin_amdgcn_exp2f(x);
#else
  return __expf(x * 0.69314718056f);
#endif
}

static __device__ __forceinline__ void gload_lds16(const void* g, void* l) {
  __builtin_amdgcn_global_load_lds(
      (const __attribute__((address_space(1))) unsigned int*)g,
      (__attribute__((address_space(3))) unsigned int*)l, 16, 0, 0);
}

// W [E][E] f32 row-major -> Wt bf16 [N=E][K=E] (transposed); y selects W.
__global__ __launch_bounds__(256) void conv_wT_all(
    const float* __restrict__ Wq, const float* __restrict__ Wk,
    const float* __restrict__ Wv, const float* __restrict__ Wo,
    short* __restrict__ Wt) {
  const float* W = (blockIdx.y == 0) ? Wq
                   : ((blockIdx.y == 1) ? Wk : ((blockIdx.y == 2) ? Wv : Wo));
  short* o = Wt + (size_t)blockIdx.y * (E_ * E_);
  int idx = blockIdx.x * 256 + threadIdx.x;
  int j = idx >> 9, k = idx & 511;
  o[idx] = f2bf(W[(size_t)k * E_ + j]);
}

// ------- GEMM core (bf16 A): 2-phase dbuf, BK=32, frag-gathered LDS -------
static __device__ __forceinline__ void gemm_core_512(
    const short* __restrict__ A, const short* __restrict__ Bt,
    short* As, short* Bs, int tm, int tn, f32x4 acc[4][4]) {
  const int tid = threadIdx.x;
  const int wave = tid >> 6, lane = tid & 63;
  const int c = lane & 15, g = lane >> 4;
  int fOff[2];
#pragma unroll
  for (int r = 0; r < 2; ++r) {
    const int f = wave * 2 + r;  // frag 0..7
    fOff[r] = ((f >> 2) * 64 + (f & 3) * 16 + c) * 512 + g * 8;
  }
  auto stg = [&](int p, int b) {
#pragma unroll
    for (int r = 0; r < 2; ++r) {
      const int f = wave * 2 + r;
      gload_lds16(A + (size_t)tm * 512 + p * 32 + fOff[r],
                  (char*)As + b * 8192 + f * 1024);
      gload_lds16(Bt + (size_t)tn * 512 + p * 32 + fOff[r],
                  (char*)Bs + b * 8192 + f * 1024);
    }
  };
  stg(0, 0);
  __syncthreads();
  for (int p = 0; p < 16; ++p) {
    if (p + 1 < 16) stg(p + 1, (p + 1) & 1);  // overlaps compute below
    const short* Ac = As + (p & 1) * 4096;
    const short* Bc = Bs + (p & 1) * 4096;
    s16x8 af[4], bfr[4];
#pragma unroll
    for (int i = 0; i < 4; ++i)
      af[i] = *(const s16x8*)(Ac + ((wave >> 1) * 4 + i) * 512 + lane * 8);
#pragma unroll
    for (int j = 0; j < 4; ++j)
      bfr[j] = *(const s16x8*)(Bc + ((wave & 1) * 4 + j) * 512 + lane * 8);
#pragma unroll
    for (int i = 0; i < 4; ++i)
#pragma unroll
      for (int j = 0; j < 4; ++j)
        acc[i][j] = mfma32(af[i], bfr[j], acc[i][j]);
    __syncthreads();
  }
}

// ------- GEMM core (f32 A, fused conversion): T14 reg-staged A ------------
static __device__ __forceinline__ void gemm_core_f32A(
    const float* __restrict__ A, const short* __restrict__ Bt,
    short* As, short* Bs, int tm, int tn, f32x4 acc[4][4]) {
  const int tid = threadIdx.x;
  const int wave = tid >> 6, lane = tid & 63;
  const int c = lane & 15, g = lane >> 4;
  int fOff[2];
#pragma unroll
  for (int r = 0; r < 2; ++r) {
    const int f = wave * 2 + r;
    fOff[r] = ((f >> 2) * 64 + (f & 3) * 16 + c) * 512 + g * 8;
  }
  auto stgB = [&](int p, int b) {
#pragma unroll
    for (int r = 0; r < 2; ++r)
      gload_lds16(Bt + (size_t)tn * 512 + p * 32 + fOff[r],
                  (char*)Bs + b * 8192 + (wave * 2 + r) * 1024);
  };
  float4 a0[2], a1[2];
  auto ldA = [&](int p) {
#pragma unroll
    for (int r = 0; r < 2; ++r) {
      const float* ap = A + (size_t)tm * 512 + p * 32 + fOff[r];
      a0[r] = *(const float4*)ap;
      a1[r] = *(const float4*)(ap + 4);
    }
  };
  auto wrA = [&](int b) {
#pragma unroll
    for (int r = 0; r < 2; ++r) {
      s16x8 w;
      w[0] = f2bf(a0[r].x); w[1] = f2bf(a0[r].y);
      w[2] = f2bf(a0[r].z); w[3] = f2bf(a0[r].w);
      w[4] = f2bf(a1[r].x); w[5] = f2bf(a1[r].y);
      w[6] = f2bf(a1[r].z); w[7] = f2bf(a1[r].w);
      *(s16x8*)((char*)As + b * 8192 + (wave * 2 + r) * 1024 + lane * 16) = w;
    }
  };
  ldA(0); stgB(0, 0); wrA(0);
  __syncthreads();
  for (int p = 0; p < 16; ++p) {
    if (p + 1 < 16) { ldA(p + 1); stgB(p + 1, (p + 1) & 1); }
    const short* Ac = As + (p & 1) * 4096;
    const short* Bc = Bs + (p & 1) * 4096;
    s16x8 af[4], bfr[4];
#pragma unroll
    for (int i = 0; i < 4; ++i)
      af[i] = *(const s16x8*)(Ac + ((wave >> 1) * 4 + i) * 512 + lane * 8);
#pragma unroll
    for (int j = 0; j < 4; ++j)
      bfr[j] = *(const s16x8*)(Bc + ((wave & 1) * 4 + j) * 512 + lane * 8);
#pragma unroll
    for (int i = 0; i < 4; ++i)
#pragma unroll
      for (int j = 0; j < 4; ++j)
        acc[i][j] = mfma32(af[i], bfr[j], acc[i][j]);
    if (p + 1 < 16) wrA((p + 1) & 1);  // into the buffer freed last barrier
    __syncthreads();
  }
}

// QKV projections from the ORIGINAL f32 inputs (conv pass fused away).
__global__ __launch_bounds__(256) void gemm_qkv(
    const float* __restrict__ Xq, const float* __restrict__ Xk,
    const float* __restrict__ Xv, const short* __restrict__ Wt,
    const float* __restrict__ bq, const float* __restrict__ bk,
    const float* __restrict__ bv,
    short* __restrict__ Qo, short* __restrict__ Ko, short* __restrict__ Vto) {
  __shared__ __align__(16) short As[2 * 4096];
  __shared__ __align__(16) short Bs[2 * 4096];
  const int z = blockIdx.z;
  const float* A = (z == 0) ? Xq : ((z == 1) ? Xk : Xv);
  const short* Bt = Wt + z * (E_ * E_);
  const float* bias = (z == 0) ? bq : ((z == 1) ? bk : bv);
  const int tm = blockIdx.x * 128, tn = blockIdx.y * 128;
  f32x4 acc[4][4] = {};
  gemm_core_f32A(A, Bt, As, Bs, tm, tn, acc);

  const int tid = threadIdx.x;
  const int wave = tid >> 6, lane = tid & 63;
  const int wm = (wave >> 1) * 64, wn = (wave & 1) * 64;
  const int c = lane & 15, g = lane >> 4;
#pragma unroll
  for (int i = 0; i < 4; ++i) {
#pragma unroll
    for (int j = 0; j < 4; ++j) {
      const int gc = tn + wn + j * 16 + c;
      const float bb = bias[gc];
      const int h = gc >> 6, dk = gc & 63;
      if (z == 2) {
        const int gr0 = tm + wm + i * 16 + g * 4;
        const int b = gr0 >> 12, s0 = gr0 & 4095;
        s16x4 v4;
#pragma unroll
        for (int r = 0; r < 4; ++r) v4[r] = f2bf(acc[i][j][r] + bb);
        *(s16x4*)&Vto[(size_t)((b * H_ + h) * DK_ + dk) * S_ + s0] = v4;
      } else {
#pragma unroll
        for (int r = 0; r < 4; ++r) {
          const int gr = tm + wm + i * 16 + g * 4 + r;
          const int b = gr >> 12, s = gr & 4095;
          float v = acc[i][j][r] + bb;
          if (z == 0) v *= 1.44269504f;  // Q *= log2(e)
          const short hv = f2bf(v);
          if (z == 1)
            Ko[(size_t)((b * H_ + h) * S_ + s) * DK_ + dk] = hv;
          else
            Qo[(size_t)((b * H_ + h) * S_ + s) * DK_ + dk] = hv;
        }
      }
    }
  }
}

// Output projection: out = AO(bf16) @ Wo + bo, f32 row-major.
__global__ __launch_bounds__(256) void gemm_out(
    const short* __restrict__ AO, const short* __restrict__ Wot,
    const float* __restrict__ bo, float* __restrict__ out) {
  __shared__ __align__(16) short As[2 * 4096];
  __shared__ __align__(16) short Bs[2 * 4096];
  const int tm = blockIdx.x * 128, tn = blockIdx.y * 128;
  f32x4 acc[4][4] = {};
  gemm_core_512(AO, Wot, As, Bs, tm, tn, acc);

  const int tid = threadIdx.x;
  const int wave = tid >> 6, lane = tid & 63;
  const int wm = (wave >> 1) * 64, wn = (wave & 1) * 64;
  const int c = lane & 15, g = lane >> 4;
#pragma unroll
  for (int i = 0; i < 4; ++i) {
#pragma unroll
    for (int j = 0; j < 4; ++j) {
      const int gc = tn + wn + j * 16 + c;
      const float bb = bo[gc];
#pragma unroll
      for (int r = 0; r < 4; ++r) {
        const int gr = tm + wm + i * 16 + g * 4 + r;
        out[(size_t)gr * E_ + gc] = acc[i][j][r] + bb;
      }
    }
  }
}

// ---- flash attention: r17 race-free schedule, UNBRACKETED clusters -------
// r17 measured pipes still near-serialized (Mfma 46 + VALU 33 + LDS ~28 ≈
// 107%) despite qk(t+1) being independent of softpv(t). Suspect: the
// s_setprio(1/0) intrinsics bracketing every MFMA cluster are side-effecting
// scheduling fences — the compiler cannot migrate qk(t+1)'s MFMAs into
// softpv(t)'s VALU stretch across them. This round: NO setprio anywhere;
// each window is one straight-line region {qk(t); qk(t+1); softpv(t);
// softpv(t+1)} and the list scheduler is free to interleave.
// Also: denominator back to per-lane VALU sums (r14) — drops 4 MFMA/tile,
// balancing matrix (~1033cyc) vs VALU (~1030cyc) poles so the max-pipe
// floor is minimized if overlap materializes.
// Everything else = r17: 8 waves = 4 qg(64q) x 2 kh, 256 q/block, 1
// block/CU (r16: 4 waves/SIMD spills), 2-tile windows, K/V 6-buffered,
// race-free epoch schedule (stage only after full-drain barrier), no-max
// softmax (Q pre-scaled log2e), key-half merge via dead-LDS overlay.
__global__ __launch_bounds__(512, 2) void attn_fwd(
    const short* __restrict__ Q, const short* __restrict__ K,
    const short* __restrict__ Vt, short* __restrict__ O) {
  __shared__ __align__(16) char lds[98304];  // K 6x8K | V 6x8K; merge overlay
  const int tid = threadIdx.x;
  const int wave = tid >> 6, lane = tid & 63;
  const int g = wave >> 1, kh = wave & 1;
  const int qi = lane & 31, hi = lane >> 5;
  const int bh = blockIdx.y;
  const int b = bh >> 3, h = bh & 7;
  const int q0 = blockIdx.x * 256 + g * 64;
  const short* Qp = Q + (size_t)bh * S_ * DK_;
  const short* Kp = K + (size_t)bh * S_ * DK_;
  const short* Vp = Vt + (size_t)bh * DK_ * S_;

  s16x8 qfL[4], qfH[4];
#pragma unroll
  for (int s = 0; s < 4; ++s) {
    qfL[s] = *(const s16x8*)(Qp + (size_t)(q0 + qi) * DK_ + s * 16 + hi * 8);
    qfH[s] = *(const s16x8*)(Qp + (size_t)(q0 + 32 + qi) * DK_ + s * 16 + hi * 8);
  }

  f32x16 o00 = {}, o01 = {}, o10 = {}, o11 = {};  // o[dkh][qh]
  float lsL = 0.f, lsH = 0.f;                     // denominator partials

  // per-lane gather offsets: wave stages K frag `wave` and V frag `wave`
  int kOff, vOff;
  {
    const int j = wave;                    // 0..7
    const int row = (j >> 2) * 32 + qi;    // K source row (pre-tau)
    const int srow = (row & 32) | ((row & 8) << 1) | ((row & 4) << 1) |
                     ((row & 16) >> 2) | (row & 3);  // tau permute
    kOff = srow * DK_ + (j & 3) * 16 + hi * 8;
    vOff = ((j >> 2) * 32 + qi) * S_ + ((j >> 1) & 1) * 32 +
           (j & 1) * 16 + hi * 8;
  }

  // stage tile kt: K frags -> lds[(kt%6)*8K], V frags -> lds[48K+(kt%6)*8K]
  auto stage = [&](int kt) {
    gload_lds16(Kp + (size_t)kt * 64 * DK_ + kOff,
                lds + (kt % 6) * 8192 + wave * 1024);
    gload_lds16(Vp + (size_t)kt * 64 + vOff,
                lds + 49152 + (kt % 6) * 8192 + wave * 1024);
  };

  // full-drain barrier: all DMA landed, all LDS reads done, then sync.
  auto barD = [&]() {
    asm volatile("s_waitcnt vmcnt(0) lgkmcnt(0)" ::: "memory");
    __builtin_amdgcn_s_barrier();
  };

  const int lbK = kh * 4096 + (lane << 4);

  auto qk = [&](int t, f32x16& sL, f32x16& sH) {
    const char* Kc = lds + (t % 6) * 8192 + lbK;
    f32x16 a = {}, c = {};
#pragma unroll
    for (int s = 0; s < 4; ++s) {
      s16x8 ka = *(const s16x8*)(Kc + s * 1024);
      a = mfma3232(ka, qfL[s], a);
      c = mfma3232(ka, qfH[s], c);
    }
    sL = a; sH = c;
  };

  auto softpv = [&](const f32x16& sL, const f32x16& sH, int t) {
    const char* Vc = lds + 49152 + (t % 6) * 8192 + kh * 2048 + (lane << 4);
    float pL[16], pH[16];
#pragma unroll
    for (int r = 0; r < 16; ++r) { pL[r] = fastexp2(sL[r]); pH[r] = fastexp2(sH[r]); }
    float aL = 0.f, aH = 0.f;
#pragma unroll
    for (int r = 0; r < 16; ++r) { aL += pL[r]; aH += pH[r]; }
    lsL += aL; lsH += aH;
    s16x8 pbL[2], pbH[2];
#pragma unroll
    for (int ks = 0; ks < 2; ++ks)
#pragma unroll
      for (int j = 0; j < 8; ++j) {
        const int r = (j & 3) | (ks << 2) | ((j >> 2) << 3);
        pbL[ks][j] = f2bf(pL[r]);
        pbH[ks][j] = f2bf(pH[r]);
      }
#pragma unroll
    for (int ks = 0; ks < 2; ++ks) {
      s16x8 va0 = *(const s16x8*)(Vc + ks * 1024);          // dk 0-31
      s16x8 va1 = *(const s16x8*)(Vc + 4096 + ks * 1024);   // dk 32-63
      o00 = mfma3232(va0, pbL[ks], o00);
      o01 = mfma3232(va0, pbH[ks], o01);
      o10 = mfma3232(va1, pbL[ks], o10);
      o11 = mfma3232(va1, pbH[ks], o11);
    }
  };

  const int NT = S_ / 64;
  f32x16 sA0, sA1, sB0, sB1;

  // prologue: tiles 0..3 staged + fully drained
  stage(0); stage(1); stage(2); stage(3);
  barD();

  for (int t = 0; t < NT; t += 2) {
    qk(t, sA0, sA1);
    qk(t + 1, sB0, sB1);   // independent of softpv(t): scheduler may overlap
    softpv(sA0, sA1, t);
    softpv(sB0, sB1, t + 1);
    barD();  // all reads of t,t+1 done block-wide; DMA t+2,t+3 landed
    if (t + 4 < NT) { stage(t + 4); stage(t + 5); }  // overwrite is SAFE
  }

  // fold the two hi-slices (16 keys each) of this key-half
  lsL += __shfl_xor(lsL, 32);
  lsH += __shfl_xor(lsH, 32);

  // ---- key-half merge: plain addition (no-max softmax partials exact) ----
  float* mrg = (float*)lds;
  const int mi = (g * 64 + lane) * 36;
  __syncthreads();  // no DMA outstanding (last barD); all waves past loop
  if (kh) {
#pragma unroll
    for (int r = 0; r < 4; ++r) {
      *(f32x4*)(mrg + mi + r * 4) =
          f32x4{o00[r * 4], o00[r * 4 + 1], o00[r * 4 + 2], o00[r * 4 + 3]};
      *(f32x4*)(mrg + mi + 16 + r * 4) =
          f32x4{o01[r * 4], o01[r * 4 + 1], o01[r * 4 + 2], o01[r * 4 + 3]};
    }
    mrg[mi + 32] = lsL;
    mrg[mi + 33] = lsH;
  }
  __syncthreads();
  float rlL = 0.f, rlH = 0.f;
  if (!kh) {
    float dL = lsL, dH = lsH;
#pragma unroll
    for (int r = 0; r < 16; ++r) {
      o00[r] += mrg[mi + r];
      o01[r] += mrg[mi + 16 + r];
    }
    dL += mrg[mi + 32];
    dH += mrg[mi + 33];
    rlL = 1.f / dL;
    rlH = 1.f / dH;
  }
  __syncthreads();
  if (kh) {
#pragma unroll
    for (int r = 0; r < 4; ++r) {
      *(f32x4*)(mrg + mi + r * 4) =
          f32x4{o10[r * 4], o10[r * 4 + 1], o10[r * 4 + 2], o10[r * 4 + 3]};
      *(f32x4*)(mrg + mi + 16 + r * 4) =
          f32x4{o11[r * 4], o11[r * 4 + 1], o11[r * 4 + 2], o11[r * 4 + 3]};
    }
  }
  __syncthreads();
  if (!kh) {
#pragma unroll
    for (int r = 0; r < 16; ++r) {
      o10[r] += mrg[mi + r];
      o11[r] += mrg[mi + 16 + r];
    }
    // write out: q row = q0 + qh*32 + qi; dk = dkh*32 + rr*8 + hi*4 + e
    short* OpL = O + ((size_t)(b * S_ + q0 + qi)) * E_ + h * DK_;
    short* OpH = O + ((size_t)(b * S_ + q0 + 32 + qi)) * E_ + h * DK_;
#pragma unroll
    for (int rr = 0; rr < 4; ++rr) {
      s16x4 vL0, vL1, vH0, vH1;
#pragma unroll
      for (int e = 0; e < 4; ++e) {
        vL0[e] = f2bf(o00[rr * 4 + e] * rlL);
        vL1[e] = f2bf(o10[rr * 4 + e] * rlL);
        vH0[e] = f2bf(o01[rr * 4 + e] * rlH);
        vH1[e] = f2bf(o11[rr * 4 + e] * rlH);
      }
      *(s16x4*)(OpL + rr * 8 + hi * 4) = vL0;
      *(s16x4*)(OpL + 32 + rr * 8 + hi * 4) = vL1;
      *(s16x4*)(OpH + rr * 8 + hi * 4) = vH0;
      *(s16x4*)(OpH + 32 + rr * 8 + hi * 4) = vH1;
    }
  }
}

// ---------------- launch ----------------
extern "C" void kernel_launch(void* const* d_in, const int* in_sizes, int n_in,
                              void* d_out, int out_size, void* d_ws, size_t ws_size,
                              hipStream_t stream) {
  const float* query  = (const float*)d_in[0];
  const float* key_in = (const float*)d_in[1];
  const float* value  = (const float*)d_in[2];
  const float* Wq = (const float*)d_in[3];
  const float* bq = (const float*)d_in[4];
  const float* Wk = (const float*)d_in[5];
  const float* bk = (const float*)d_in[6];
  const float* Wv = (const float*)d_in[7];
  const float* bv = (const float*)d_in[8];
  const float* Wo = (const float*)d_in[9];
  const float* bo = (const float*)d_in[10];
  float* out = (float*)d_out;

  const size_t NA = (size_t)M_ * E_;  // 4,194,304
  short* ws  = (short*)d_ws;
  short* Wt  = ws;                    // bf16 W^T, q/k/v/o fused [4E][E]
  short* Wot = Wt + 3 * E_ * E_;
  short* Qb  = Wt + 4 * E_ * E_;      // bf16 [B,H,S,DK] (pre-scaled log2e)
  short* Kb  = Qb + NA;               // bf16 [B,H,S,DK]
  short* Vtb = Kb + NA;               // bf16 [B,H,DK,S]
  short* AO  = Vtb + NA;              // bf16 attn out [B,S,E]

  conv_wT_all<<<dim3(E_ * E_ / 256, 4), 256, 0, stream>>>(Wq, Wk, Wv, Wo, Wt);

  gemm_qkv<<<dim3(M_ / 128, E_ / 128, 3), 256, 0, stream>>>(
      query, key_in, value, Wt, bq, bk, bv, Qb, Kb, Vtb);
  attn_fwd<<<dim3(S_ / 256, B_ * H_), 512, 0, stream>>>(Qb, Kb, Vtb, AO);
  gemm_out<<<dim3(M_ / 128, E_ / 128), 256, 0, stream>>>(AO, Wot, bo, out);
}